// Round 11
// baseline (19787.224 us; speedup 1.0000x reference)
//
#include <hip/hip_runtime.h>

typedef __bf16 bf16;
typedef __bf16 bf16x8 __attribute__((ext_vector_type(8)));
typedef __bf16 bf16x4 __attribute__((ext_vector_type(4)));
typedef float  f32x4  __attribute__((ext_vector_type(4)));

#define T_DIM 256
#define B_DIM 1024
#define HID   256
#define G4    1024
#define KIMG  784
#define KPAD  800
#define CTXD  64
#define MROWS (T_DIM*B_DIM)
#define WPITCH 264

__device__ __forceinline__ void gll16(const void* g, void* l) {
  __builtin_amdgcn_global_load_lds((const __attribute__((address_space(1))) void*)g,
                                   (__attribute__((address_space(3))) void*)l, 16, 0, 0);
}
__device__ __forceinline__ float sigm(float x) { return 1.f / (1.f + __expf(-x)); }
__device__ __forceinline__ float tanh_(float x) {
  x = fminf(fmaxf(x, -15.f), 15.f);
  float e = __expf(2.f * x);
  return (e - 1.f) / (e + 1.f);
}

// ---------------- prep kernels ----------------
__global__ void k_wiT(const float* __restrict__ wi, bf16* __restrict__ wiT) {
  int n = blockIdx.x;
  for (int k = threadIdx.x; k < KPAD; k += 256) {
    float v = (k < KIMG) ? wi[(long)k * G4 + n] : 0.f;
    wiT[(long)n * KPAD + k] = (bf16)v;
  }
}
__global__ void k_whT(const float* __restrict__ wh, bf16* __restrict__ whT) {
  int n = blockIdx.x;
  int k = threadIdx.x;
  whT[n * HID + k] = (bf16)wh[k * G4 + n];
}
__global__ void k_W0T(const float* __restrict__ a0k, const float* __restrict__ cr0k,
                      bf16* __restrict__ w0t) {
  int n = blockIdx.x;
  int k = threadIdx.x;
  float v = (n < 32) ? a0k[k * 32 + n] : cr0k[k * 32 + (n - 32)];
  w0t[n * HID + k] = (bf16)v;
}
__global__ void k_dirgate(const float* __restrict__ wi, const float* __restrict__ emb_k,
                          const float* __restrict__ emb_b, const float* __restrict__ b_lstm,
                          float* __restrict__ dir_gate) {
  int d = blockIdx.x;
  for (int n = threadIdx.x; n < G4; n += 256) {
    float s = b_lstm[n];
#pragma unroll
    for (int j = 0; j < 5; ++j) s += (emb_k[d * 5 + j] + emb_b[j]) * wi[(KIMG + j) * G4 + n];
    dir_gate[d * G4 + n] = s;
  }
}
__global__ void k_ctxgate(const float* __restrict__ wi, const float* __restrict__ ctx,
                          float* __restrict__ ctx_gate) {
  int b = blockIdx.x;
  __shared__ float cs[CTXD];
  if (threadIdx.x < CTXD) cs[threadIdx.x] = ctx[b * CTXD + threadIdx.x];
  __syncthreads();
  for (int n = threadIdx.x; n < G4; n += 256) {
    float s = 0.f;
#pragma unroll 8
    for (int k = 0; k < CTXD; ++k) s += cs[k] * wi[(KIMG + 5 + k) * G4 + n];
    ctx_gate[(long)b * G4 + n] = s;
  }
}

// ---------------- conv ----------------
#define CONV_ROWS 8
__global__ void k_conv(const float* __restrict__ img, const float* __restrict__ ck,
                       const float* __restrict__ cb, bf16* __restrict__ out) {
  __shared__ float s_img[CONV_ROWS * 243];
  __shared__ float s_k[432];
  __shared__ float s_b[16];
  long r0 = (long)blockIdx.x * CONV_ROWS;
  const float* src = img + r0 * 243;
  for (int i = threadIdx.x; i < CONV_ROWS * 243; i += 256) s_img[i] = src[i];
  for (int i = threadIdx.x; i < 432; i += 256) s_k[i] = ck[i];
  if (threadIdx.x < 16) s_b[threadIdx.x] = cb[threadIdx.x];
  __syncthreads();
  for (int idx = threadIdx.x; idx < CONV_ROWS * KPAD; idx += 256) {
    int r = idx / KPAD, c = idx % KPAD;
    float v = 0.f;
    if (c < KIMG) {
      int pix = c >> 4, ch = c & 15;
      int oy = pix / 7, ox = pix % 7;
      const float* ib = s_img + r * 243 + (oy * 9 + ox) * 3;
      v = s_b[ch];
#pragma unroll
      for (int ky = 0; ky < 3; ++ky)
#pragma unroll
        for (int kx = 0; kx < 3; ++kx)
#pragma unroll
          for (int cc = 0; cc < 3; ++cc)
            v += ib[(ky * 9 + kx) * 3 + cc] * s_k[((ky * 3 + kx) * 3 + cc) * 16 + ch];
      v = fmaxf(v, 0.f);
    }
    out[r0 * KPAD + idx] = (bf16)v;
  }
}

// ---------------- big GEMM: xg (gate-PLANAR: xg[g][t*B+b][u]) ----------------
__global__ __launch_bounds__(256, 2)
void k_gemm_xg(const bf16* __restrict__ A, const bf16* __restrict__ Bt,
               const float* __restrict__ dir_gate, const float* __restrict__ ctx_gate,
               const int* __restrict__ agent_dir, bf16* __restrict__ xg) {
  __shared__ __align__(16) bf16 As[128 * 32];
  __shared__ __align__(16) bf16 Bs[128 * 32];
  const int bid = blockIdx.x;
  const int xcd = bid & 7, local = bid >> 3;
  const long m0 = (long)(xcd * 256 + (local >> 3)) * 128;
  const int n0 = (local & 7) * 128;
  const int tid = threadIdx.x, wave = tid >> 6, lane = tid & 63;
  const int row16 = lane & 15, k8 = (lane >> 4) * 8, rowg = (lane >> 4) * 4;
  const int wr = (wave >> 1) * 64, wc = (wave & 1) * 64;

  const bf16* a_src0 = A + (m0 + tid / 4) * KPAD + (tid % 4) * 8;
  const bf16* a_src1 = A + (m0 + 64 + tid / 4) * KPAD + (tid % 4) * 8;
  const bf16* b_src0 = Bt + (long)(n0 + tid / 4) * KPAD + (tid % 4) * 8;
  const bf16* b_src1 = Bt + (long)(n0 + 64 + tid / 4) * KPAD + (tid % 4) * 8;
  bf16* asd0 = As + wave * 512;
  bf16* asd1 = As + 2048 + wave * 512;
  bf16* bsd0 = Bs + wave * 512;
  bf16* bsd1 = Bs + 2048 + wave * 512;

  f32x4 acc[4][4];
  const f32x4 zero = {0.f, 0.f, 0.f, 0.f};
#pragma unroll
  for (int i = 0; i < 4; ++i)
#pragma unroll
    for (int j = 0; j < 4; ++j) acc[i][j] = zero;

  for (int ks = 0; ks < 25; ++ks) {
    const int ko = ks * 32;
    gll16(a_src0 + ko, asd0);
    gll16(a_src1 + ko, asd1);
    gll16(b_src0 + ko, bsd0);
    gll16(b_src1 + ko, bsd1);
    __syncthreads();
    bf16x8 af[4], bfr[4];
#pragma unroll
    for (int i = 0; i < 4; ++i)
      af[i] = *(const bf16x8*)(As + (wr + 16 * i + row16) * 32 + k8);
#pragma unroll
    for (int j = 0; j < 4; ++j)
      bfr[j] = *(const bf16x8*)(Bs + (wc + 16 * j + row16) * 32 + k8);
#pragma unroll
    for (int i = 0; i < 4; ++i)
#pragma unroll
      for (int j = 0; j < 4; ++j)
        acc[i][j] = __builtin_amdgcn_mfma_f32_16x16x32_bf16(af[i], bfr[j], acc[i][j], 0, 0, 0);
    __syncthreads();
  }
#pragma unroll
  for (int i = 0; i < 4; ++i)
#pragma unroll
    for (int j = 0; j < 4; ++j)
#pragma unroll
      for (int r = 0; r < 4; ++r) {
        long row = m0 + wr + 16 * i + rowg + r;
        int colj = n0 + wc + 16 * j + row16;
        int dv = agent_dir[row];
        float base = dir_gate[dv * G4 + colj] + ctx_gate[(long)(row & 1023) * G4 + colj];
        int u = colj & 255, g = colj >> 8;
        xg[((long)g * MROWS + row) * 256 + u] = (bf16)(acc[i][j][r] + base);
      }
}

// ---------------- LSTM scan: 4-gate cross-block split ----------------
// 256 blocks = 64 groups x 4 gate-blocks. Block (G, ga) holds gate ga's FULL
// 256x256 bf16 weights LDS-resident (135 KB) -> ZERO weight streaming.
// Per step: each block computes P_ga = h @ W_ga^T + x_ga for its group's 16
// batch rows, publishes the 8 KB bf16 tile via L2/IC with a parity-double-
// buffered flag protocol (skew bound: 1 step), then all 4 blocks redundantly
// run the elementwise epilogue (c replicated; own gate used bf16-rounded =
// bit-identical to what partners read). ga==0 writes ys/cfin/hfin.
__global__ __launch_bounds__(512)
void k_lstm(const bf16* __restrict__ xg, const bf16* __restrict__ whT,
            const int* __restrict__ dones,
            const float* __restrict__ c0, const float* __restrict__ h0,
            bf16* __restrict__ ys, float* __restrict__ cfin, float* __restrict__ hfin,
            bf16* __restrict__ pex, int* __restrict__ flags) {
  __shared__ __align__(16) bf16 wc_lds[256 * WPITCH];   // this block's gate weights
  __shared__ __align__(16) bf16 h_lds[16 * WPITCH];
  const int tid = threadIdx.x;
  const int w = tid >> 6, lane = tid & 63;
  const int col = lane & 15;
  const int k8 = (lane >> 4) * 8;
  const int rowg = (lane >> 4) * 4;
  const int G = blockIdx.x & 63, ga = blockIdx.x >> 6;
  const int b0 = G * 16;
  const int ju = 32 * w + col;

  // resident weights for gate ga
  const bf16* wsrc = whT + (long)ga * 256 * HID;
  for (int i = tid; i < 256 * 32; i += 512) {
    int row = i >> 5, chunk = i & 31;
    *(bf16x8*)(wc_lds + row * WPITCH + chunk * 8) =
        *(const bf16x8*)(wsrc + row * HID + chunk * 8);
  }
  for (int i = tid; i < 16 * HID; i += 512) {
    int m = i >> 8, j = i & 255;
    h_lds[m * WPITCH + j] = (bf16)h0[(b0 + m) * HID + j];
  }
  float creg[2][4], c0reg[2][4];
  bf16 h0b[2][4];
#pragma unroll
  for (int q = 0; q < 2; ++q)
#pragma unroll
    for (int r = 0; r < 4; ++r) {
      int j = ju + 16 * q;
      float v = c0[(b0 + rowg + r) * HID + j];
      creg[q][r] = v; c0reg[q][r] = v;
      h0b[q][r] = (bf16)h0[(b0 + rowg + r) * HID + j];
    }
  const bf16* xplane = xg + (long)ga * MROWS * 256;

  // prologue: done(0), own-plane x(0)
  int4 dnA = *(const int4*)(dones + b0 + rowg);
  float xc[2][4];
#pragma unroll
  for (int q = 0; q < 2; ++q)
#pragma unroll
    for (int r = 0; r < 4; ++r)
      xc[q][r] = (float)xplane[(long)(b0 + rowg + r) * 256 + ju + 16 * q];
  __syncthreads();

#pragma unroll 1
  for (int t = 0; t < T_DIM; ++t) {
    const int tn = (t + 1 < T_DIM) ? t + 1 : (T_DIM - 1);
    f32x4 acc[2];
    const f32x4 zero = {0.f, 0.f, 0.f, 0.f};
    acc[0] = zero; acc[1] = zero;

    float xn[2][4];
    int4 dnB;
#pragma unroll
    for (int ks = 0; ks < 8; ++ks) {
      bf16x8 a = *(const bf16x8*)(h_lds + col * WPITCH + ks * 32 + k8);
#pragma unroll
      for (int q = 0; q < 2; ++q) {
        bf16x8 bi = *(const bf16x8*)(wc_lds + (ju + 16 * q) * WPITCH + ks * 32 + k8);
        acc[q] = __builtin_amdgcn_mfma_f32_16x16x32_bf16(a, bi, acc[q], 0, 0, 0);
      }
      if (ks == 2) {
#pragma unroll
        for (int q = 0; q < 2; ++q)
#pragma unroll
          for (int r = 0; r < 4; ++r)
            xn[q][r] = (float)xplane[((long)tn * B_DIM + b0 + rowg + r) * 256 + ju + 16 * q];
        dnB = *(const int4*)(dones + (long)tn * B_DIM + b0 + rowg);
      }
    }
    // own pre-activation, bf16-rounded (identical bits to what partners read)
    bf16 pown[2][4];
    {
      bf16* pdst = pex + (((long)(t & 1) * 4 + ga) * 64 + G) * 4096;
#pragma unroll
      for (int q = 0; q < 2; ++q)
#pragma unroll
        for (int r = 0; r < 4; ++r) {
          pown[q][r] = (bf16)(acc[q][r] + xc[q][r]);
          pdst[(rowg + r) * 256 + ju + 16 * q] = pown[q][r];
        }
    }
    __syncthreads();   // drains vmcnt(0): P stores in L2; h_lds reads complete
    if (tid == 0) {
      __threadfence();  // push P to device-visible point (agent scope)
      __hip_atomic_store(&flags[(t & 1) * 256 + G * 4 + ga], t + 1,
                         __ATOMIC_RELEASE, __HIP_MEMORY_SCOPE_AGENT);
    }
    if (tid < 3) {
      int pg = tid + (tid >= ga ? 1 : 0);
      int* fp = &flags[(t & 1) * 256 + G * 4 + pg];
      int it = 0;
      while (__hip_atomic_load(fp, __ATOMIC_ACQUIRE, __HIP_MEMORY_SCOPE_AGENT) < t + 1) {
        if (++it > (1 << 21)) break;   // co-residency safety: fail, don't hang
        __builtin_amdgcn_s_sleep(2);
      }
    }
    __syncthreads();
    __threadfence();   // acquire side: invalidate caches before partner reads

    int dc[4] = {dnA.x, dnA.y, dnA.z, dnA.w};
    int dx[4] = {dnB.x, dnB.y, dnB.z, dnB.w};
    const bf16* pbase = pex + ((long)(t & 1) * 4 * 64 + G) * 4096;
#pragma unroll
    for (int q = 0; q < 2; ++q)
#pragma unroll
      for (int r = 0; r < 4; ++r) {
        const int off = (rowg + r) * 256 + ju + 16 * q;
        float g4[4];
#pragma unroll
        for (int pg = 0; pg < 4; ++pg)
          g4[pg] = (pg == ga) ? (float)pown[q][r]
                              : (float)pbase[(long)pg * 64 * 4096 + off];
        float c_old = dc[r] ? c0reg[q][r] : creg[q][r];
        float cn = sigm(g4[1]) * c_old + sigm(g4[0]) * tanh_(g4[2]);
        float hn = sigm(g4[3]) * tanh_(cn);
        creg[q][r] = cn;
        int m = rowg + r, j = ju + 16 * q;
        bf16 hb = (bf16)hn;
        h_lds[m * WPITCH + j] = dx[r] ? h0b[q][r] : hb;
        if (ga == 0) {
          ys[((long)t * B_DIM + b0 + m) * HID + j] = hb;
          if (t == T_DIM - 1) {
            cfin[(b0 + m) * HID + j] = cn;
            hfin[(b0 + m) * HID + j] = hn;
          }
        }
      }
#pragma unroll
    for (int q = 0; q < 2; ++q)
#pragma unroll
      for (int r = 0; r < 4; ++r) xc[q][r] = xn[q][r];
    dnA = dnB;
    __syncthreads();   // h_lds visible before next step's GEMM
  }
}

// ---------------- fused heads: ys @ W0 -> relu -> @ W1 -> logits/value ----
#define H1PITCH 66
__global__ __launch_bounds__(256, 2)
void k_heads(const bf16* __restrict__ ys, const bf16* __restrict__ w0t,
             const float* __restrict__ a0b, const float* __restrict__ cr0b,
             const float* __restrict__ a1k, const float* __restrict__ a1b,
             const float* __restrict__ cr1k, const float* __restrict__ cr1b,
             float* __restrict__ logits, float* __restrict__ value) {
  __shared__ __align__(16) bf16 As[128 * 32];
  __shared__ __align__(16) bf16 Ws[64 * 264];
  __shared__ bf16 h1_lds[128 * H1PITCH];
  __shared__ float w2[32 * 8];
  const int tid = threadIdx.x, wave = tid >> 6, lane = tid & 63;
  const int row16 = lane & 15, k8 = (lane >> 4) * 8, rowg = (lane >> 4) * 4;
  const long m0 = (long)blockIdx.x * 128;
  for (int i = tid; i < 64 * 256; i += 256) {
    int n = i >> 8, k = i & 255;
    Ws[n * 264 + k] = w0t[i];
  }
  if (tid < 224) { int k = tid / 7, c = tid % 7; w2[k * 8 + c] = a1k[tid]; }
  else if (tid < 256) { int k = tid - 224; w2[k * 8 + 7] = cr1k[k]; }
  const bf16* a_src0 = ys + (m0 + tid / 4) * HID + (tid % 4) * 8;
  const bf16* a_src1 = ys + (m0 + 64 + tid / 4) * HID + (tid % 4) * 8;
  bf16* asd0 = As + wave * 512;
  bf16* asd1 = As + 2048 + wave * 512;
  f32x4 acc[2][4];
  const f32x4 zero = {0.f, 0.f, 0.f, 0.f};
#pragma unroll
  for (int i = 0; i < 2; ++i)
#pragma unroll
    for (int j = 0; j < 4; ++j) acc[i][j] = zero;
  for (int ks = 0; ks < 8; ++ks) {
    gll16(a_src0 + ks * 32, asd0);
    gll16(a_src1 + ks * 32, asd1);
    __syncthreads();
    bf16x8 bw[4];
#pragma unroll
    for (int j = 0; j < 4; ++j)
      bw[j] = *(const bf16x8*)(Ws + (16 * j + row16) * 264 + ks * 32 + k8);
#pragma unroll
    for (int i = 0; i < 2; ++i) {
      bf16x8 a = *(const bf16x8*)(As + (32 * wave + 16 * i + row16) * 32 + k8);
#pragma unroll
      for (int j = 0; j < 4; ++j)
        acc[i][j] = __builtin_amdgcn_mfma_f32_16x16x32_bf16(a, bw[j], acc[i][j], 0, 0, 0);
    }
    __syncthreads();
  }
#pragma unroll
  for (int i = 0; i < 2; ++i)
#pragma unroll
    for (int j = 0; j < 4; ++j)
#pragma unroll
      for (int r = 0; r < 4; ++r) {
        int rl = 32 * wave + 16 * i + rowg + r;
        int n = 16 * j + row16;
        float bias = (n < 32) ? a0b[n] : cr0b[n - 32];
        h1_lds[rl * H1PITCH + n] = (bf16)fmaxf(acc[i][j][r] + bias, 0.f);
      }
  __syncthreads();
  if (tid < 128) {
    const bf16* hp = h1_lds + tid * H1PITCH;
    float acc7[7];
#pragma unroll
    for (int c = 0; c < 7; ++c) acc7[c] = a1b[c];
    float accv = cr1b[0];
#pragma unroll 4
    for (int k = 0; k < 32; ++k) {
      float av = (float)hp[k];
      float cv = (float)hp[32 + k];
#pragma unroll
      for (int c = 0; c < 7; ++c) acc7[c] += av * w2[k * 8 + c];
      accv += cv * w2[k * 8 + 7];
    }
    long row = m0 + tid;
#pragma unroll
    for (int c = 0; c < 7; ++c) logits[row * 7 + c] = acc7[c];
    value[row] = accv;
  }
}

// ---------------- launch ----------------
extern "C" void kernel_launch(void* const* d_in, const int* in_sizes, int n_in,
                              void* d_out, int out_size, void* d_ws, size_t ws_size,
                              hipStream_t stream) {
  const float* image = (const float*)d_in[0];
  const int* agent_dir = (const int*)d_in[1];
  const int* dones = (const int*)d_in[2];
  const float* context = (const float*)d_in[3];
  const float* c0 = (const float*)d_in[4];
  const float* h0 = (const float*)d_in[5];
  const float* conv_k = (const float*)d_in[6];
  const float* conv_b = (const float*)d_in[7];
  const float* emb_k = (const float*)d_in[8];
  const float* emb_b = (const float*)d_in[9];
  const float* wi = (const float*)d_in[10];
  const float* wh = (const float*)d_in[11];
  const float* b_lstm = (const float*)d_in[12];
  const float* a0_k = (const float*)d_in[13];
  const float* a0_b = (const float*)d_in[14];
  const float* a1_k = (const float*)d_in[15];
  const float* a1_b = (const float*)d_in[16];
  const float* cr0_k = (const float*)d_in[17];
  const float* cr0_b = (const float*)d_in[18];
  const float* cr1_k = (const float*)d_in[19];
  const float* cr1_b = (const float*)d_in[20];

  char* ws = (char*)d_ws;
  const size_t off_conv = 0;                              // conv_out region; ys reuse
  const size_t off_xg   = 419430400ULL;
  const size_t off_wiT  = off_xg  + 536870912ULL;
  const size_t off_whT  = off_wiT + 1638400ULL;
  const size_t off_W0T  = off_whT + 524288ULL;
  const size_t off_dirg = off_W0T + 32768ULL;             // 16 KB; flags reuse after gemm
  const size_t off_ctxg = off_dirg + 16384ULL;            // 4 MB; pex reuse after gemm
  const size_t total    = off_ctxg + 4194304ULL;
  if (ws_size < total) return;

  bf16* conv_out = (bf16*)(ws + off_conv);
  bf16* xg       = (bf16*)(ws + off_xg);
  bf16* wiT      = (bf16*)(ws + off_wiT);
  bf16* whT      = (bf16*)(ws + off_whT);
  bf16* W0T      = (bf16*)(ws + off_W0T);
  float* dir_gate = (float*)(ws + off_dirg);
  float* ctx_gate = (float*)(ws + off_ctxg);
  bf16* pex  = (bf16*)(ws + off_ctxg);      // reuses ctx_gate (dead after gemm), 4 MB exact
  int*  flags = (int*)(ws + off_dirg);      // reuses dir_gate (dead after gemm), 2 KB
  bf16* ys = (bf16*)(ws + 0);               // reuses conv_out region (dead after GEMM)

  float* out_cfin = (float*)d_out;
  float* out_hfin = out_cfin + 262144;
  float* out_logits = out_cfin + 524288;
  float* out_value = out_cfin + 524288 + 1835008;

  k_wiT<<<1024, 256, 0, stream>>>(wi, wiT);
  k_whT<<<1024, 256, 0, stream>>>(wh, whT);
  k_W0T<<<64, 256, 0, stream>>>(a0_k, cr0_k, W0T);
  k_dirgate<<<4, 256, 0, stream>>>(wi, emb_k, emb_b, b_lstm, dir_gate);
  k_ctxgate<<<1024, 256, 0, stream>>>(wi, context, ctx_gate);
  k_conv<<<MROWS / CONV_ROWS, 256, 0, stream>>>(image, conv_k, conv_b, conv_out);
  k_gemm_xg<<<16384, 256, 0, stream>>>(conv_out, wiT, dir_gate, ctx_gate, agent_dir, xg);
  hipMemsetAsync(flags, 0, 2048, stream);   // reset exchange flags each launch
  k_lstm<<<256, 512, 0, stream>>>(xg, whT, dones, c0, h0, ys, out_cfin, out_hfin,
                                  pex, flags);
  k_heads<<<2048, 256, 0, stream>>>(ys, W0T, a0_b, cr0_b, a1_k, a1_b, cr1_k, cr1_b,
                                    out_logits, out_value);
}

// Round 12
// 2830.080 us; speedup vs baseline: 6.9918x; 6.9918x over previous
//
#include <hip/hip_runtime.h>
#include <hip/hip_fp8.h>

typedef __bf16 bf16;
typedef __bf16 bf16x8 __attribute__((ext_vector_type(8)));
typedef __bf16 bf16x4 __attribute__((ext_vector_type(4)));
typedef float  f32x4  __attribute__((ext_vector_type(4)));

#define T_DIM 256
#define B_DIM 1024
#define HID   256
#define G4    1024
#define KIMG  784
#define KPAD  800
#define KEXT  864
#define CTXD  64
#define MROWS (T_DIM*B_DIM)
#define WPITCH 264

__device__ __forceinline__ void gll16(const void* g, void* l) {
  __builtin_amdgcn_global_load_lds((const __attribute__((address_space(1))) void*)g,
                                   (__attribute__((address_space(3))) void*)l, 16, 0, 0);
}
__device__ __forceinline__ float sigm(float x) { return 1.f / (1.f + __expf(-x)); }
__device__ __forceinline__ float tanh_(float x) {
  x = fminf(fmaxf(x, -15.f), 15.f);
  float e = __expf(2.f * x);
  return (e - 1.f) / (e + 1.f);
}
__device__ __forceinline__ void bar_lds() {
  asm volatile("s_waitcnt lgkmcnt(0)\n\ts_barrier" ::: "memory");
}
__device__ __forceinline__ unsigned char to_fp8(float f) {
  __hip_fp8_e4m3 v(f);
  return *reinterpret_cast<unsigned char*>(&v);
}

// ---------------- prep kernels ----------------
// wiT[n][k], k in [0,864): 0..783 img weights; 784..799 zero; 800..863 ctx
// weights (wi rows 789..852). dir-emb (wi rows 784..788) + b_lstm live in
// dir_gate (epilogue).
__global__ void k_wiT(const float* __restrict__ wi, bf16* __restrict__ wiT) {
  int n = blockIdx.x;
  for (int k = threadIdx.x; k < KEXT; k += 256) {
    float v = 0.f;
    if (k < KIMG) v = wi[(long)k * G4 + n];
    else if (k >= 800) v = wi[(long)(k - 11) * G4 + n];  // 789 + (k-800)
    wiT[(long)n * KEXT + k] = (bf16)v;
  }
}
// ext[b][c] = (bf16)context[b][c] — A-columns 800..863, 128 KB L2-hot table
__global__ void k_ext(const float* __restrict__ ctx, bf16* __restrict__ ext) {
  int idx = blockIdx.x * 256 + threadIdx.x;
  ext[idx] = (bf16)ctx[idx];
}
__global__ void k_whT(const float* __restrict__ wh, bf16* __restrict__ whT) {
  int n = blockIdx.x;
  int k = threadIdx.x;
  whT[n * HID + k] = (bf16)wh[k * G4 + n];
}
__global__ void k_wh8(const float* __restrict__ wh, unsigned char* __restrict__ wh8) {
  int n = blockIdx.x;
  int k = threadIdx.x;
  wh8[n * HID + k]         = to_fp8(wh[k * G4 + 256 + n]);  // gate f
  wh8[65536 + n * HID + k] = to_fp8(wh[k * G4 + 768 + n]);  // gate o
}
__global__ void k_W0T(const float* __restrict__ a0k, const float* __restrict__ cr0k,
                      bf16* __restrict__ w0t) {
  int n = blockIdx.x;
  int k = threadIdx.x;
  float v = (n < 32) ? a0k[k * 32 + n] : cr0k[k * 32 + (n - 32)];
  w0t[n * HID + k] = (bf16)v;
}
__global__ void k_dirgate(const float* __restrict__ wi, const float* __restrict__ emb_k,
                          const float* __restrict__ emb_b, const float* __restrict__ b_lstm,
                          float* __restrict__ dir_gate) {
  int d = blockIdx.x;
  for (int n = threadIdx.x; n < G4; n += 256) {
    float s = b_lstm[n];
#pragma unroll
    for (int j = 0; j < 5; ++j) s += (emb_k[d * 5 + j] + emb_b[j]) * wi[(KIMG + j) * G4 + n];
    dir_gate[d * G4 + n] = s;
  }
}

// ---------------- conv ----------------
#define CONV_ROWS 8
__global__ void k_conv(const float* __restrict__ img, const float* __restrict__ ck,
                       const float* __restrict__ cb, bf16* __restrict__ out) {
  __shared__ float s_img[CONV_ROWS * 243];
  __shared__ float s_k[432];
  __shared__ float s_b[16];
  long r0 = (long)blockIdx.x * CONV_ROWS;
  const float* src = img + r0 * 243;
  for (int i = threadIdx.x; i < CONV_ROWS * 243; i += 256) s_img[i] = src[i];
  for (int i = threadIdx.x; i < 432; i += 256) s_k[i] = ck[i];
  if (threadIdx.x < 16) s_b[threadIdx.x] = cb[threadIdx.x];
  __syncthreads();
  for (int idx = threadIdx.x; idx < CONV_ROWS * KPAD; idx += 256) {
    int r = idx / KPAD, c = idx % KPAD;
    float v = 0.f;
    if (c < KIMG) {
      int pix = c >> 4, ch = c & 15;
      int oy = pix / 7, ox = pix % 7;
      const float* ib = s_img + r * 243 + (oy * 9 + ox) * 3;
      v = s_b[ch];
#pragma unroll
      for (int ky = 0; ky < 3; ++ky)
#pragma unroll
        for (int kx = 0; kx < 3; ++kx)
#pragma unroll
          for (int cc = 0; cc < 3; ++cc)
            v += ib[(ky * 9 + kx) * 3 + cc] * s_k[((ky * 3 + kx) * 3 + cc) * 16 + ch];
      v = fmaxf(v, 0.f);
    }
    out[r0 * KPAD + idx] = (bf16)v;
  }
}

// ---------------- big GEMM: xg = [conv | ctx] @ wiT^T + dir_gate ----------
// K = 864 = 25 conv K-steps (stride 800) + 2 ext K-steps (ext[row&1023]).
// Output layout: xg[(t*B + b)*1024 + unit*4 + gate]
__global__ __launch_bounds__(256, 2)
void k_gemm_xg(const bf16* __restrict__ A, const bf16* __restrict__ ext,
               const bf16* __restrict__ Bt, const float* __restrict__ dir_gate,
               const int* __restrict__ agent_dir, bf16* __restrict__ xg) {
  __shared__ __align__(16) bf16 As[128 * 32];
  __shared__ __align__(16) bf16 Bs[128 * 32];
  const int bid = blockIdx.x;
  const int xcd = bid & 7, local = bid >> 3;
  const long m0 = (long)(xcd * 256 + (local >> 3)) * 128;
  const int n0 = (local & 7) * 128;
  const int tid = threadIdx.x, wave = tid >> 6, lane = tid & 63;
  const int row16 = lane & 15, k8 = (lane >> 4) * 8, rowg = (lane >> 4) * 4;
  const int wr = (wave >> 1) * 64, wc = (wave & 1) * 64;

  const bf16* a_src0 = A + (m0 + tid / 4) * KPAD + (tid % 4) * 8;
  const bf16* a_src1 = A + (m0 + 64 + tid / 4) * KPAD + (tid % 4) * 8;
  // ctx extension rows: b = row & 1023 (no wrap within a 64-row half-tile)
  const bf16* e_src0 = ext + (long)(((m0) & 1023) + tid / 4) * CTXD + (tid % 4) * 8;
  const bf16* e_src1 = ext + (long)(((m0 + 64) & 1023) + tid / 4) * CTXD + (tid % 4) * 8;
  const bf16* b_src0 = Bt + (long)(n0 + tid / 4) * KEXT + (tid % 4) * 8;
  const bf16* b_src1 = Bt + (long)(n0 + 64 + tid / 4) * KEXT + (tid % 4) * 8;
  bf16* asd0 = As + wave * 512;
  bf16* asd1 = As + 2048 + wave * 512;
  bf16* bsd0 = Bs + wave * 512;
  bf16* bsd1 = Bs + 2048 + wave * 512;

  f32x4 acc[4][4];
  const f32x4 zero = {0.f, 0.f, 0.f, 0.f};
#pragma unroll
  for (int i = 0; i < 4; ++i)
#pragma unroll
    for (int j = 0; j < 4; ++j) acc[i][j] = zero;

  for (int ks = 0; ks < 27; ++ks) {
    if (ks < 25) {
      const int ko = ks * 32;
      gll16(a_src0 + ko, asd0);
      gll16(a_src1 + ko, asd1);
    } else {
      const int ko = (ks - 25) * 32;
      gll16(e_src0 + ko, asd0);
      gll16(e_src1 + ko, asd1);
    }
    const int kb = ks * 32;
    gll16(b_src0 + kb, bsd0);
    gll16(b_src1 + kb, bsd1);
    __syncthreads();
    bf16x8 af[4], bfr[4];
#pragma unroll
    for (int i = 0; i < 4; ++i)
      af[i] = *(const bf16x8*)(As + (wr + 16 * i + row16) * 32 + k8);
#pragma unroll
    for (int j = 0; j < 4; ++j)
      bfr[j] = *(const bf16x8*)(Bs + (wc + 16 * j + row16) * 32 + k8);
#pragma unroll
    for (int i = 0; i < 4; ++i)
#pragma unroll
      for (int j = 0; j < 4; ++j)
        acc[i][j] = __builtin_amdgcn_mfma_f32_16x16x32_bf16(af[i], bfr[j], acc[i][j], 0, 0, 0);
    __syncthreads();
  }
#pragma unroll
  for (int i = 0; i < 4; ++i)
#pragma unroll
    for (int j = 0; j < 4; ++j)
#pragma unroll
      for (int r = 0; r < 4; ++r) {
        long row = m0 + wr + 16 * i + rowg + r;
        int colj = n0 + wc + 16 * j + row16;
        int dv = agent_dir[row];
        float base = dir_gate[dv * G4 + colj];   // 16 KB, L1-resident
        int u = colj & 255, g = colj >> 8;
        xg[row * G4 + u * 4 + g] = (bf16)(acc[i][j][r] + base);
      }
}

// ---------------- LSTM scan (R10 structure — best known: 1455 us) ----------
// gate i: bf16 LDS-resident; gate g: bf16 streamed; gates f,o: fp8 streamed.
// h in LDS in bf16 + fp8. Raw lgkm-only barriers. 256 KB/step streamed.
__global__ __launch_bounds__(512)
void k_lstm(const bf16* __restrict__ xg, const bf16* __restrict__ whT,
            const unsigned char* __restrict__ wh8,
            const int* __restrict__ dones,
            const float* __restrict__ c0, const float* __restrict__ h0,
            bf16* __restrict__ ys, float* __restrict__ cfin, float* __restrict__ hfin) {
  __shared__ __align__(16) bf16 h_lds[16 * WPITCH];
  __shared__ __align__(16) unsigned char h8_lds[16 * WPITCH];
  __shared__ __align__(16) bf16 wc_lds[256 * WPITCH];
  const int tid = threadIdx.x;
  const int w = tid >> 6, lane = tid & 63;
  const int col = lane & 15;
  const int kq = lane >> 4;
  const int k8 = kq * 8;
  const int rowg = kq * 4;
  const int b0 = blockIdx.x * 16;
  const int ju = 32 * w + col;

  for (int i = tid; i < 256 * 32; i += 512) {
    int row = i >> 5, chunk = i & 31;
    *(bf16x8*)(wc_lds + row * WPITCH + chunk * 8) =
        *(const bf16x8*)(whT + row * HID + chunk * 8);
  }
  for (int i = tid; i < 16 * HID; i += 512) {
    int m = i >> 8, j = i & 255;
    float v = h0[(b0 + m) * HID + j];
    h_lds[m * WPITCH + j] = (bf16)v;
    h8_lds[m * WPITCH + j] = to_fp8(v);
  }

  float creg[2][4], c0reg[2][4];
  bf16 h0b[2][4];
  unsigned char h0b8[2][4];
#pragma unroll
  for (int q = 0; q < 2; ++q)
#pragma unroll
    for (int r = 0; r < 4; ++r) {
      int j = ju + 16 * q;
      float v = c0[(b0 + rowg + r) * HID + j];
      creg[q][r] = v; c0reg[q][r] = v;
      float hv = h0[(b0 + rowg + r) * HID + j];
      h0b[q][r] = (bf16)hv;
      h0b8[q][r] = to_fp8(hv);
    }
  const bf16* wgp[2];
  const unsigned char* wfp[2];
  const unsigned char* wop[2];
#pragma unroll
  for (int q = 0; q < 2; ++q) {
    wgp[q] = whT + (long)(512 + ju + 16 * q) * HID + k8;
    wfp[q] = wh8 + (ju + 16 * q) * HID + k8;
    wop[q] = wh8 + 65536 + (ju + 16 * q) * HID + k8;
  }

  int4 dnA = *(const int4*)(dones + b0 + rowg);
  bf16x4 xc[2][4];
  {
    const bf16* xb = xg + (long)(b0 + rowg) * G4 + ju * 4;
#pragma unroll
    for (int q = 0; q < 2; ++q)
#pragma unroll
      for (int r = 0; r < 4; ++r)
        xc[q][r] = *(const bf16x4*)(xb + (long)r * G4 + 64 * q);
  }
  bf16x8 bg_cur[2], bg_nxt[2];
  long long bf_cur[2], bf_nxt[2], bo_cur[2], bo_nxt[2];
#pragma unroll
  for (int q = 0; q < 2; ++q) {
    bg_cur[q] = *(const bf16x8*)(wgp[q]);
    bf_cur[q] = *(const long long*)(wfp[q]);
    bo_cur[q] = *(const long long*)(wop[q]);
  }
  __syncthreads();

#pragma unroll 1
  for (int t = 0; t < T_DIM; ++t) {
    const int tn = (t + 1 < T_DIM) ? t + 1 : (T_DIM - 1);
    f32x4 acc[4][2];
    const f32x4 zero = {0.f, 0.f, 0.f, 0.f};
#pragma unroll
    for (int g = 0; g < 4; ++g) { acc[g][0] = zero; acc[g][1] = zero; }

    int4 dnB;
#pragma unroll
    for (int ks = 0; ks < 8; ++ks) {
      {
        const int kn = (ks + 1) & 7;
#pragma unroll
        for (int q = 0; q < 2; ++q) {
          bg_nxt[q] = *(const bf16x8*)(wgp[q] + kn * 32);
          bf_nxt[q] = *(const long long*)(wfp[q] + kn * 32);
          bo_nxt[q] = *(const long long*)(wop[q] + kn * 32);
        }
      }
      bf16x8 a = *(const bf16x8*)(h_lds + col * WPITCH + ks * 32 + k8);
      long long a8 = *(const long long*)(h8_lds + col * WPITCH + ks * 32 + k8);
#pragma unroll
      for (int q = 0; q < 2; ++q) {
        bf16x8 bi = *(const bf16x8*)(wc_lds + (ju + 16 * q) * WPITCH + ks * 32 + k8);
        acc[0][q] = __builtin_amdgcn_mfma_f32_16x16x32_bf16(a, bi, acc[0][q], 0, 0, 0);
      }
#pragma unroll
      for (int q = 0; q < 2; ++q) {
        acc[1][q] = __builtin_amdgcn_mfma_f32_16x16x32_fp8_fp8(a8, bf_cur[q], acc[1][q], 0, 0, 0);
        acc[2][q] = __builtin_amdgcn_mfma_f32_16x16x32_bf16(a, bg_cur[q], acc[2][q], 0, 0, 0);
        acc[3][q] = __builtin_amdgcn_mfma_f32_16x16x32_fp8_fp8(a8, bo_cur[q], acc[3][q], 0, 0, 0);
        bg_cur[q] = bg_nxt[q]; bf_cur[q] = bf_nxt[q]; bo_cur[q] = bo_nxt[q];
      }
      if (ks == 2)
        dnB = *(const int4*)(dones + (long)tn * B_DIM + b0 + rowg);
    }
    bar_lds();

    int dc[4] = {dnA.x, dnA.y, dnA.z, dnA.w};
    int dx[4] = {dnB.x, dnB.y, dnB.z, dnB.w};
#pragma unroll
    for (int q = 0; q < 2; ++q)
#pragma unroll
      for (int r = 0; r < 4; ++r) {
        float c_old = dc[r] ? c0reg[q][r] : creg[q][r];
        float gi = acc[0][q][r] + (float)xc[q][r][0];
        float gf = acc[1][q][r] + (float)xc[q][r][1];
        float gg = acc[2][q][r] + (float)xc[q][r][2];
        float go = acc[3][q][r] + (float)xc[q][r][3];
        float cn = sigm(gf) * c_old + sigm(gi) * tanh_(gg);
        float hn = sigm(go) * tanh_(cn);
        creg[q][r] = cn;
        int m = rowg + r, j = ju + 16 * q;
        bf16 hb = (bf16)hn;
        ys[((long)t * B_DIM + b0 + m) * HID + j] = hb;
        h_lds[m * WPITCH + j] = dx[r] ? h0b[q][r] : hb;
        h8_lds[m * WPITCH + j] = dx[r] ? h0b8[q][r] : to_fp8(hn);
        if (t == T_DIM - 1) {
          cfin[(b0 + m) * HID + j] = cn;
          hfin[(b0 + m) * HID + j] = hn;
        }
      }
    {
      const bf16* xb = xg + (long)(tn * B_DIM + b0 + rowg) * G4 + ju * 4;
#pragma unroll
      for (int q = 0; q < 2; ++q)
#pragma unroll
        for (int r = 0; r < 4; ++r)
          xc[q][r] = *(const bf16x4*)(xb + (long)r * G4 + 64 * q);
    }
    dnA = dnB;
    bar_lds();
  }
}

// ---------------- fused heads ----------------
#define H1PITCH 66
__global__ __launch_bounds__(256, 2)
void k_heads(const bf16* __restrict__ ys, const bf16* __restrict__ w0t,
             const float* __restrict__ a0b, const float* __restrict__ cr0b,
             const float* __restrict__ a1k, const float* __restrict__ a1b,
             const float* __restrict__ cr1k, const float* __restrict__ cr1b,
             float* __restrict__ logits, float* __restrict__ value) {
  __shared__ __align__(16) bf16 As[128 * 32];
  __shared__ __align__(16) bf16 Ws[64 * 264];
  __shared__ bf16 h1_lds[128 * H1PITCH];
  __shared__ float w2[32 * 8];
  const int tid = threadIdx.x, wave = tid >> 6, lane = tid & 63;
  const int row16 = lane & 15, k8 = (lane >> 4) * 8, rowg = (lane >> 4) * 4;
  const long m0 = (long)blockIdx.x * 128;
  for (int i = tid; i < 64 * 256; i += 256) {
    int n = i >> 8, k = i & 255;
    Ws[n * 264 + k] = w0t[i];
  }
  if (tid < 224) { int k = tid / 7, c = tid % 7; w2[k * 8 + c] = a1k[tid]; }
  else if (tid < 256) { int k = tid - 224; w2[k * 8 + 7] = cr1k[k]; }
  const bf16* a_src0 = ys + (m0 + tid / 4) * HID + (tid % 4) * 8;
  const bf16* a_src1 = ys + (m0 + 64 + tid / 4) * HID + (tid % 4) * 8;
  bf16* asd0 = As + wave * 512;
  bf16* asd1 = As + 2048 + wave * 512;
  f32x4 acc[2][4];
  const f32x4 zero = {0.f, 0.f, 0.f, 0.f};
#pragma unroll
  for (int i = 0; i < 2; ++i)
#pragma unroll
    for (int j = 0; j < 4; ++j) acc[i][j] = zero;
  for (int ks = 0; ks < 8; ++ks) {
    gll16(a_src0 + ks * 32, asd0);
    gll16(a_src1 + ks * 32, asd1);
    __syncthreads();
    bf16x8 bw[4];
#pragma unroll
    for (int j = 0; j < 4; ++j)
      bw[j] = *(const bf16x8*)(Ws + (16 * j + row16) * 264 + ks * 32 + k8);
#pragma unroll
    for (int i = 0; i < 2; ++i) {
      bf16x8 a = *(const bf16x8*)(As + (32 * wave + 16 * i + row16) * 32 + k8);
#pragma unroll
      for (int j = 0; j < 4; ++j)
        acc[i][j] = __builtin_amdgcn_mfma_f32_16x16x32_bf16(a, bw[j], acc[i][j], 0, 0, 0);
    }
    __syncthreads();
  }
#pragma unroll
  for (int i = 0; i < 2; ++i)
#pragma unroll
    for (int j = 0; j < 4; ++j)
#pragma unroll
      for (int r = 0; r < 4; ++r) {
        int rl = 32 * wave + 16 * i + rowg + r;
        int n = 16 * j + row16;
        float bias = (n < 32) ? a0b[n] : cr0b[n - 32];
        h1_lds[rl * H1PITCH + n] = (bf16)fmaxf(acc[i][j][r] + bias, 0.f);
      }
  __syncthreads();
  if (tid < 128) {
    const bf16* hp = h1_lds + tid * H1PITCH;
    float acc7[7];
#pragma unroll
    for (int c = 0; c < 7; ++c) acc7[c] = a1b[c];
    float accv = cr1b[0];
#pragma unroll 4
    for (int k = 0; k < 32; ++k) {
      float av = (float)hp[k];
      float cv = (float)hp[32 + k];
#pragma unroll
      for (int c = 0; c < 7; ++c) acc7[c] += av * w2[k * 8 + c];
      accv += cv * w2[k * 8 + 7];
    }
    long row = m0 + tid;
#pragma unroll
    for (int c = 0; c < 7; ++c) logits[row * 7 + c] = acc7[c];
    value[row] = accv;
  }
}

// ---------------- launch ----------------
extern "C" void kernel_launch(void* const* d_in, const int* in_sizes, int n_in,
                              void* d_out, int out_size, void* d_ws, size_t ws_size,
                              hipStream_t stream) {
  const float* image = (const float*)d_in[0];
  const int* agent_dir = (const int*)d_in[1];
  const int* dones = (const int*)d_in[2];
  const float* context = (const float*)d_in[3];
  const float* c0 = (const float*)d_in[4];
  const float* h0 = (const float*)d_in[5];
  const float* conv_k = (const float*)d_in[6];
  const float* conv_b = (const float*)d_in[7];
  const float* emb_k = (const float*)d_in[8];
  const float* emb_b = (const float*)d_in[9];
  const float* wi = (const float*)d_in[10];
  const float* wh = (const float*)d_in[11];
  const float* b_lstm = (const float*)d_in[12];
  const float* a0_k = (const float*)d_in[13];
  const float* a0_b = (const float*)d_in[14];
  const float* a1_k = (const float*)d_in[15];
  const float* a1_b = (const float*)d_in[16];
  const float* cr0_k = (const float*)d_in[17];
  const float* cr0_b = (const float*)d_in[18];
  const float* cr1_k = (const float*)d_in[19];
  const float* cr1_b = (const float*)d_in[20];

  char* ws = (char*)d_ws;
  const size_t off_conv = 0;                              // 419,430,400 (ys reuse)
  const size_t off_xg   = 419430400ULL;                   // 512 MB
  const size_t off_wiT  = off_xg  + 536870912ULL;         // 956,301,312; 1024*864*2
  const size_t off_W0T  = off_wiT + 1769472ULL;           // 958,070,784
  const size_t off_dirg = off_W0T + 32768ULL;             // 958,103,552
  const size_t off_wh8  = off_dirg + 16384ULL;            // 958,119,936
  const size_t off_ext  = off_wh8 + 131072ULL;            // 958,251,008
  const size_t total    = off_ext + 131072ULL;            // 958,382,080
  if (ws_size < total) return;

  bf16* conv_out = (bf16*)(ws + off_conv);
  bf16* xg       = (bf16*)(ws + off_xg);
  bf16* wiT      = (bf16*)(ws + off_wiT);
  bf16* W0T      = (bf16*)(ws + off_W0T);
  float* dir_gate = (float*)(ws + off_dirg);
  unsigned char* wh8 = (unsigned char*)(ws + off_wh8);
  bf16* ext = (bf16*)(ws + off_ext);
  bf16* whT = (bf16*)(ws + off_wiT);  // placeholder; real whT below
  // whT needs its own 512 KB: carve from conv region head after gemm? No —
  // whT is live during lstm while ys (conv region) is being written. Keep a
  // dedicated slot: reuse tail of conv region NOT used by ys (ys = 128 MB).
  whT = (bf16*)(ws + 150000000ULL);   // inside conv region, beyond ys (134.2 MB), dead after gemm? conv dead after gemm; ys starts at 0 (134 MB). 150 MB offset is safe.
  bf16* ys = (bf16*)(ws + 0);

  float* out_cfin = (float*)d_out;
  float* out_hfin = out_cfin + 262144;
  float* out_logits = out_cfin + 524288;
  float* out_value = out_cfin + 524288 + 1835008;

  k_wiT<<<1024, 256, 0, stream>>>(wi, wiT);
  k_ext<<<256, 256, 0, stream>>>(context, ext);
  k_W0T<<<64, 256, 0, stream>>>(a0_k, cr0_k, W0T);
  k_dirgate<<<4, 256, 0, stream>>>(wi, emb_k, emb_b, b_lstm, dir_gate);
  k_wh8<<<256, 256, 0, stream>>>(wh, wh8);
  k_conv<<<MROWS / CONV_ROWS, 256, 0, stream>>>(image, conv_k, conv_b, conv_out);
  k_gemm_xg<<<16384, 256, 0, stream>>>(conv_out, ext, wiT, dir_gate, agent_dir, xg);
  // whT built AFTER gemm (its slot aliases conv_out, which gemm still reads)
  k_whT<<<1024, 256, 0, stream>>>(wh, whT);
  k_lstm<<<64, 512, 0, stream>>>(xg, whT, wh8, dones, c0, h0, ys, out_cfin, out_hfin);
  k_heads<<<2048, 256, 0, stream>>>(ys, W0T, a0_b, cr0_b, a1_k, a1_b, cr1_k, cr1_b,
                                    out_logits, out_value);
}

// Round 13
// 2558.075 us; speedup vs baseline: 7.7352x; 1.1063x over previous
//
#include <hip/hip_runtime.h>
#include <hip/hip_fp8.h>

typedef __bf16 bf16;
typedef __bf16 bf16x8 __attribute__((ext_vector_type(8)));
typedef __bf16 bf16x4 __attribute__((ext_vector_type(4)));
typedef float  f32x4  __attribute__((ext_vector_type(4)));

#define T_DIM 256
#define B_DIM 1024
#define HID   256
#define G4    1024
#define KIMG  784
#define KPAD  800
#define KEXT  864
#define CTXD  64
#define MROWS (T_DIM*B_DIM)
#define WPITCH 264

__device__ __forceinline__ void gll16(const void* g, void* l) {
  __builtin_amdgcn_global_load_lds((const __attribute__((address_space(1))) void*)g,
                                   (__attribute__((address_space(3))) void*)l, 16, 0, 0);
}
__device__ __forceinline__ float sigm(float x) { return 1.f / (1.f + __expf(-x)); }
__device__ __forceinline__ float tanh_(float x) {
  x = fminf(fmaxf(x, -15.f), 15.f);
  float e = __expf(2.f * x);
  return (e - 1.f) / (e + 1.f);
}
__device__ __forceinline__ void bar_lds() {
  asm volatile("s_waitcnt lgkmcnt(0)\n\ts_barrier" ::: "memory");
}
__device__ __forceinline__ unsigned char to_fp8(float f) {
  __hip_fp8_e4m3 v(f);
  return *reinterpret_cast<unsigned char*>(&v);
}

// ---------------- prep kernels ----------------
// wiT[n][k], k in [0,864): 0..783 img weights; 784..799 zero; 800..863 ctx
// weights (wi rows 789..852).
__global__ void k_wiT(const float* __restrict__ wi, bf16* __restrict__ wiT) {
  int n = blockIdx.x;
  for (int k = threadIdx.x; k < KEXT; k += 256) {
    float v = 0.f;
    if (k < KIMG) v = wi[(long)k * G4 + n];
    else if (k >= 800) v = wi[(long)(k - 11) * G4 + n];  // 789 + (k-800)
    wiT[(long)n * KEXT + k] = (bf16)v;
  }
}
__global__ void k_ext(const float* __restrict__ ctx, bf16* __restrict__ ext) {
  int idx = blockIdx.x * 256 + threadIdx.x;
  ext[idx] = (bf16)ctx[idx];
}
// fp8 e4m3 copies of ALL FOUR gate weight blocks, gate-major [g][n][k]
__global__ void k_wh8(const float* __restrict__ wh, unsigned char* __restrict__ wh8) {
  int n = blockIdx.x;
  int k = threadIdx.x;
#pragma unroll
  for (int g = 0; g < 4; ++g)
    wh8[g * 65536 + n * 256 + k] = to_fp8(wh[k * G4 + g * 256 + n]);
}
__global__ void k_W0T(const float* __restrict__ a0k, const float* __restrict__ cr0k,
                      bf16* __restrict__ w0t) {
  int n = blockIdx.x;
  int k = threadIdx.x;
  float v = (n < 32) ? a0k[k * 32 + n] : cr0k[k * 32 + (n - 32)];
  w0t[n * HID + k] = (bf16)v;
}
__global__ void k_dirgate(const float* __restrict__ wi, const float* __restrict__ emb_k,
                          const float* __restrict__ emb_b, const float* __restrict__ b_lstm,
                          float* __restrict__ dir_gate) {
  int d = blockIdx.x;
  for (int n = threadIdx.x; n < G4; n += 256) {
    float s = b_lstm[n];
#pragma unroll
    for (int j = 0; j < 5; ++j) s += (emb_k[d * 5 + j] + emb_b[j]) * wi[(KIMG + j) * G4 + n];
    dir_gate[d * G4 + n] = s;
  }
}

// ---------------- conv ----------------
#define CONV_ROWS 8
__global__ void k_conv(const float* __restrict__ img, const float* __restrict__ ck,
                       const float* __restrict__ cb, bf16* __restrict__ out) {
  __shared__ float s_img[CONV_ROWS * 243];
  __shared__ float s_k[432];
  __shared__ float s_b[16];
  long r0 = (long)blockIdx.x * CONV_ROWS;
  const float* src = img + r0 * 243;
  for (int i = threadIdx.x; i < CONV_ROWS * 243; i += 256) s_img[i] = src[i];
  for (int i = threadIdx.x; i < 432; i += 256) s_k[i] = ck[i];
  if (threadIdx.x < 16) s_b[threadIdx.x] = cb[threadIdx.x];
  __syncthreads();
  for (int idx = threadIdx.x; idx < CONV_ROWS * KPAD; idx += 256) {
    int r = idx / KPAD, c = idx % KPAD;
    float v = 0.f;
    if (c < KIMG) {
      int pix = c >> 4, ch = c & 15;
      int oy = pix / 7, ox = pix % 7;
      const float* ib = s_img + r * 243 + (oy * 9 + ox) * 3;
      v = s_b[ch];
#pragma unroll
      for (int ky = 0; ky < 3; ++ky)
#pragma unroll
        for (int kx = 0; kx < 3; ++kx)
#pragma unroll
          for (int cc = 0; cc < 3; ++cc)
            v += ib[(ky * 9 + kx) * 3 + cc] * s_k[((ky * 3 + kx) * 3 + cc) * 16 + ch];
      v = fmaxf(v, 0.f);
    }
    out[r0 * KPAD + idx] = (bf16)v;
  }
}

// ---------------- big GEMM: xg = [conv | ctx] @ wiT^T + dir_gate ----------
__global__ __launch_bounds__(256, 2)
void k_gemm_xg(const bf16* __restrict__ A, const bf16* __restrict__ ext,
               const bf16* __restrict__ Bt, const float* __restrict__ dir_gate,
               const int* __restrict__ agent_dir, bf16* __restrict__ xg) {
  __shared__ __align__(16) bf16 As[128 * 32];
  __shared__ __align__(16) bf16 Bs[128 * 32];
  const int bid = blockIdx.x;
  const int xcd = bid & 7, local = bid >> 3;
  const long m0 = (long)(xcd * 256 + (local >> 3)) * 128;
  const int n0 = (local & 7) * 128;
  const int tid = threadIdx.x, wave = tid >> 6, lane = tid & 63;
  const int row16 = lane & 15, k8 = (lane >> 4) * 8, rowg = (lane >> 4) * 4;
  const int wr = (wave >> 1) * 64, wc = (wave & 1) * 64;

  const bf16* a_src0 = A + (m0 + tid / 4) * KPAD + (tid % 4) * 8;
  const bf16* a_src1 = A + (m0 + 64 + tid / 4) * KPAD + (tid % 4) * 8;
  const bf16* e_src0 = ext + (long)(((m0) & 1023) + tid / 4) * CTXD + (tid % 4) * 8;
  const bf16* e_src1 = ext + (long)(((m0 + 64) & 1023) + tid / 4) * CTXD + (tid % 4) * 8;
  const bf16* b_src0 = Bt + (long)(n0 + tid / 4) * KEXT + (tid % 4) * 8;
  const bf16* b_src1 = Bt + (long)(n0 + 64 + tid / 4) * KEXT + (tid % 4) * 8;
  bf16* asd0 = As + wave * 512;
  bf16* asd1 = As + 2048 + wave * 512;
  bf16* bsd0 = Bs + wave * 512;
  bf16* bsd1 = Bs + 2048 + wave * 512;

  f32x4 acc[4][4];
  const f32x4 zero = {0.f, 0.f, 0.f, 0.f};
#pragma unroll
  for (int i = 0; i < 4; ++i)
#pragma unroll
    for (int j = 0; j < 4; ++j) acc[i][j] = zero;

  for (int ks = 0; ks < 27; ++ks) {
    if (ks < 25) {
      const int ko = ks * 32;
      gll16(a_src0 + ko, asd0);
      gll16(a_src1 + ko, asd1);
    } else {
      const int ko = (ks - 25) * 32;
      gll16(e_src0 + ko, asd0);
      gll16(e_src1 + ko, asd1);
    }
    const int kb = ks * 32;
    gll16(b_src0 + kb, bsd0);
    gll16(b_src1 + kb, bsd1);
    __syncthreads();
    bf16x8 af[4], bfr[4];
#pragma unroll
    for (int i = 0; i < 4; ++i)
      af[i] = *(const bf16x8*)(As + (wr + 16 * i + row16) * 32 + k8);
#pragma unroll
    for (int j = 0; j < 4; ++j)
      bfr[j] = *(const bf16x8*)(Bs + (wc + 16 * j + row16) * 32 + k8);
#pragma unroll
    for (int i = 0; i < 4; ++i)
#pragma unroll
      for (int j = 0; j < 4; ++j)
        acc[i][j] = __builtin_amdgcn_mfma_f32_16x16x32_bf16(af[i], bfr[j], acc[i][j], 0, 0, 0);
    __syncthreads();
  }
#pragma unroll
  for (int i = 0; i < 4; ++i)
#pragma unroll
    for (int j = 0; j < 4; ++j)
#pragma unroll
      for (int r = 0; r < 4; ++r) {
        long row = m0 + wr + 16 * i + rowg + r;
        int colj = n0 + wc + 16 * j + row16;
        int dv = agent_dir[row];
        float base = dir_gate[dv * G4 + colj];
        int u = colj & 255, g = colj >> 8;
        xg[row * G4 + u * 4 + g] = (bf16)(acc[i][j][r] + base);
      }
}

// ---------------- LSTM scan: all-fp8 weights ----------------
// 64 blocks x 512 threads. Gates i,g: fp8 LDS-RESIDENT (67.6 KB each).
// Gates f,o: fp8 streamed (128 KB/step, wrap-around dist-1 prefetch).
// h kept in LDS as fp8 only (all 4 MFMAs consume fp8 A). No bf16 weights.
// Raw lgkm-only barriers; xg(t+1) loaded in epilogue.
__global__ __launch_bounds__(512)
void k_lstm(const bf16* __restrict__ xg, const unsigned char* __restrict__ wh8,
            const int* __restrict__ dones,
            const float* __restrict__ c0, const float* __restrict__ h0,
            bf16* __restrict__ ys, float* __restrict__ cfin, float* __restrict__ hfin) {
  __shared__ __align__(16) unsigned char wi8_lds[256 * WPITCH];  // gate i
  __shared__ __align__(16) unsigned char wg8_lds[256 * WPITCH];  // gate g
  __shared__ __align__(16) unsigned char h8_lds[16 * WPITCH];
  const int tid = threadIdx.x;
  const int w = tid >> 6, lane = tid & 63;
  const int col = lane & 15;
  const int kq = lane >> 4;
  const int k8 = kq * 8;
  const int rowg = kq * 4;
  const int b0 = blockIdx.x * 16;
  const int ju = 32 * w + col;

  // resident fp8 weight fills (gates i and g)
  for (int i = tid; i < 256 * 32; i += 512) {
    int row = i >> 5, c = i & 31;
    *(long long*)(wi8_lds + row * WPITCH + c * 8) =
        *(const long long*)(wh8 + row * 256 + c * 8);
    *(long long*)(wg8_lds + row * WPITCH + c * 8) =
        *(const long long*)(wh8 + 2 * 65536 + row * 256 + c * 8);
  }
  for (int i = tid; i < 16 * HID; i += 512) {
    int m = i >> 8, j = i & 255;
    h8_lds[m * WPITCH + j] = to_fp8(h0[(b0 + m) * HID + j]);
  }

  float creg[2][4], c0reg[2][4];
  unsigned char h0b8[2][4];
#pragma unroll
  for (int q = 0; q < 2; ++q)
#pragma unroll
    for (int r = 0; r < 4; ++r) {
      int j = ju + 16 * q;
      float v = c0[(b0 + rowg + r) * HID + j];
      creg[q][r] = v; c0reg[q][r] = v;
      h0b8[q][r] = to_fp8(h0[(b0 + rowg + r) * HID + j]);
    }
  // stream bases: f (gate 1), o (gate 3)
  const unsigned char* wfp[2];
  const unsigned char* wop[2];
#pragma unroll
  for (int q = 0; q < 2; ++q) {
    wfp[q] = wh8 + 1 * 65536 + (ju + 16 * q) * 256 + k8;
    wop[q] = wh8 + 3 * 65536 + (ju + 16 * q) * 256 + k8;
  }

  int4 dnA = *(const int4*)(dones + b0 + rowg);
  bf16x4 xc[2][4];
  {
    const bf16* xb = xg + (long)(b0 + rowg) * G4 + ju * 4;
#pragma unroll
    for (int q = 0; q < 2; ++q)
#pragma unroll
      for (int r = 0; r < 4; ++r)
        xc[q][r] = *(const bf16x4*)(xb + (long)r * G4 + 64 * q);
  }
  long long bf_cur[2], bf_nxt[2], bo_cur[2], bo_nxt[2];
#pragma unroll
  for (int q = 0; q < 2; ++q) {
    bf_cur[q] = *(const long long*)(wfp[q]);
    bo_cur[q] = *(const long long*)(wop[q]);
  }
  __syncthreads();

#pragma unroll 1
  for (int t = 0; t < T_DIM; ++t) {
    const int tn = (t + 1 < T_DIM) ? t + 1 : (T_DIM - 1);
    f32x4 acc[4][2];
    const f32x4 zero = {0.f, 0.f, 0.f, 0.f};
#pragma unroll
    for (int g = 0; g < 4; ++g) { acc[g][0] = zero; acc[g][1] = zero; }

    int4 dnB;
#pragma unroll
    for (int ks = 0; ks < 8; ++ks) {
      // wrap-around distance-1 prefetch for streamed f,o
      {
        const int kn = (ks + 1) & 7;
#pragma unroll
        for (int q = 0; q < 2; ++q) {
          bf_nxt[q] = *(const long long*)(wfp[q] + kn * 32);
          bo_nxt[q] = *(const long long*)(wop[q] + kn * 32);
        }
      }
      long long a8 = *(const long long*)(h8_lds + col * WPITCH + ks * 32 + k8);
#pragma unroll
      for (int q = 0; q < 2; ++q) {
        long long bi8 = *(const long long*)(wi8_lds + (ju + 16 * q) * WPITCH + ks * 32 + k8);
        long long bg8 = *(const long long*)(wg8_lds + (ju + 16 * q) * WPITCH + ks * 32 + k8);
        acc[0][q] = __builtin_amdgcn_mfma_f32_16x16x32_fp8_fp8(a8, bi8, acc[0][q], 0, 0, 0);
        acc[1][q] = __builtin_amdgcn_mfma_f32_16x16x32_fp8_fp8(a8, bf_cur[q], acc[1][q], 0, 0, 0);
        acc[2][q] = __builtin_amdgcn_mfma_f32_16x16x32_fp8_fp8(a8, bg8, acc[2][q], 0, 0, 0);
        acc[3][q] = __builtin_amdgcn_mfma_f32_16x16x32_fp8_fp8(a8, bo_cur[q], acc[3][q], 0, 0, 0);
      }
#pragma unroll
      for (int q = 0; q < 2; ++q) { bf_cur[q] = bf_nxt[q]; bo_cur[q] = bo_nxt[q]; }
      if (ks == 2)
        dnB = *(const int4*)(dones + (long)tn * B_DIM + b0 + rowg);
    }
    bar_lds();   // h8_lds reads complete; global loads stay in flight

    int dc[4] = {dnA.x, dnA.y, dnA.z, dnA.w};
    int dx[4] = {dnB.x, dnB.y, dnB.z, dnB.w};
#pragma unroll
    for (int q = 0; q < 2; ++q)
#pragma unroll
      for (int r = 0; r < 4; ++r) {
        float c_old = dc[r] ? c0reg[q][r] : creg[q][r];
        float gi = acc[0][q][r] + (float)xc[q][r][0];
        float gf = acc[1][q][r] + (float)xc[q][r][1];
        float gg = acc[2][q][r] + (float)xc[q][r][2];
        float go = acc[3][q][r] + (float)xc[q][r][3];
        float cn = sigm(gf) * c_old + sigm(gi) * tanh_(gg);
        float hn = sigm(go) * tanh_(cn);
        creg[q][r] = cn;
        int m = rowg + r, j = ju + 16 * q;
        ys[((long)t * B_DIM + b0 + m) * HID + j] = (bf16)hn;
        h8_lds[m * WPITCH + j] = dx[r] ? h0b8[q][r] : to_fp8(hn);
        if (t == T_DIM - 1) {
          cfin[(b0 + m) * HID + j] = cn;
          hfin[(b0 + m) * HID + j] = hn;
        }
      }
    // prefetch next step's xg (consumed next epilogue)
    {
      const bf16* xb = xg + (long)(tn * B_DIM + b0 + rowg) * G4 + ju * 4;
#pragma unroll
      for (int q = 0; q < 2; ++q)
#pragma unroll
        for (int r = 0; r < 4; ++r)
          xc[q][r] = *(const bf16x4*)(xb + (long)r * G4 + 64 * q);
    }
    dnA = dnB;
    bar_lds();   // h8 writes visible for next step's GEMM
  }
}

// ---------------- fused heads ----------------
#define H1PITCH 66
__global__ __launch_bounds__(256, 2)
void k_heads(const bf16* __restrict__ ys, const bf16* __restrict__ w0t,
             const float* __restrict__ a0b, const float* __restrict__ cr0b,
             const float* __restrict__ a1k, const float* __restrict__ a1b,
             const float* __restrict__ cr1k, const float* __restrict__ cr1b,
             float* __restrict__ logits, float* __restrict__ value) {
  __shared__ __align__(16) bf16 As[128 * 32];
  __shared__ __align__(16) bf16 Ws[64 * 264];
  __shared__ bf16 h1_lds[128 * H1PITCH];
  __shared__ float w2[32 * 8];
  const int tid = threadIdx.x, wave = tid >> 6, lane = tid & 63;
  const int row16 = lane & 15, k8 = (lane >> 4) * 8, rowg = (lane >> 4) * 4;
  const long m0 = (long)blockIdx.x * 128;
  for (int i = tid; i < 64 * 256; i += 256) {
    int n = i >> 8, k = i & 255;
    Ws[n * 264 + k] = w0t[i];
  }
  if (tid < 224) { int k = tid / 7, c = tid % 7; w2[k * 8 + c] = a1k[tid]; }
  else if (tid < 256) { int k = tid - 224; w2[k * 8 + 7] = cr1k[k]; }
  const bf16* a_src0 = ys + (m0 + tid / 4) * HID + (tid % 4) * 8;
  const bf16* a_src1 = ys + (m0 + 64 + tid / 4) * HID + (tid % 4) * 8;
  bf16* asd0 = As + wave * 512;
  bf16* asd1 = As + 2048 + wave * 512;
  f32x4 acc[2][4];
  const f32x4 zero = {0.f, 0.f, 0.f, 0.f};
#pragma unroll
  for (int i = 0; i < 2; ++i)
#pragma unroll
    for (int j = 0; j < 4; ++j) acc[i][j] = zero;
  for (int ks = 0; ks < 8; ++ks) {
    gll16(a_src0 + ks * 32, asd0);
    gll16(a_src1 + ks * 32, asd1);
    __syncthreads();
    bf16x8 bw[4];
#pragma unroll
    for (int j = 0; j < 4; ++j)
      bw[j] = *(const bf16x8*)(Ws + (16 * j + row16) * 264 + ks * 32 + k8);
#pragma unroll
    for (int i = 0; i < 2; ++i) {
      bf16x8 a = *(const bf16x8*)(As + (32 * wave + 16 * i + row16) * 32 + k8);
#pragma unroll
      for (int j = 0; j < 4; ++j)
        acc[i][j] = __builtin_amdgcn_mfma_f32_16x16x32_bf16(a, bw[j], acc[i][j], 0, 0, 0);
    }
    __syncthreads();
  }
#pragma unroll
  for (int i = 0; i < 2; ++i)
#pragma unroll
    for (int j = 0; j < 4; ++j)
#pragma unroll
      for (int r = 0; r < 4; ++r) {
        int rl = 32 * wave + 16 * i + rowg + r;
        int n = 16 * j + row16;
        float bias = (n < 32) ? a0b[n] : cr0b[n - 32];
        h1_lds[rl * H1PITCH + n] = (bf16)fmaxf(acc[i][j][r] + bias, 0.f);
      }
  __syncthreads();
  if (tid < 128) {
    const bf16* hp = h1_lds + tid * H1PITCH;
    float acc7[7];
#pragma unroll
    for (int c = 0; c < 7; ++c) acc7[c] = a1b[c];
    float accv = cr1b[0];
#pragma unroll 4
    for (int k = 0; k < 32; ++k) {
      float av = (float)hp[k];
      float cv = (float)hp[32 + k];
#pragma unroll
      for (int c = 0; c < 7; ++c) acc7[c] += av * w2[k * 8 + c];
      accv += cv * w2[k * 8 + 7];
    }
    long row = m0 + tid;
#pragma unroll
    for (int c = 0; c < 7; ++c) logits[row * 7 + c] = acc7[c];
    value[row] = accv;
  }
}

// ---------------- launch ----------------
extern "C" void kernel_launch(void* const* d_in, const int* in_sizes, int n_in,
                              void* d_out, int out_size, void* d_ws, size_t ws_size,
                              hipStream_t stream) {
  const float* image = (const float*)d_in[0];
  const int* agent_dir = (const int*)d_in[1];
  const int* dones = (const int*)d_in[2];
  const float* context = (const float*)d_in[3];
  const float* c0 = (const float*)d_in[4];
  const float* h0 = (const float*)d_in[5];
  const float* conv_k = (const float*)d_in[6];
  const float* conv_b = (const float*)d_in[7];
  const float* emb_k = (const float*)d_in[8];
  const float* emb_b = (const float*)d_in[9];
  const float* wi = (const float*)d_in[10];
  const float* wh = (const float*)d_in[11];
  const float* b_lstm = (const float*)d_in[12];
  const float* a0_k = (const float*)d_in[13];
  const float* a0_b = (const float*)d_in[14];
  const float* a1_k = (const float*)d_in[15];
  const float* a1_b = (const float*)d_in[16];
  const float* cr0_k = (const float*)d_in[17];
  const float* cr0_b = (const float*)d_in[18];
  const float* cr1_k = (const float*)d_in[19];
  const float* cr1_b = (const float*)d_in[20];

  char* ws = (char*)d_ws;
  const size_t off_conv = 0;                              // 419,430,400 (ys reuse)
  const size_t off_xg   = 419430400ULL;                   // 512 MB
  const size_t off_wiT  = off_xg  + 536870912ULL;         // 1024*864*2
  const size_t off_W0T  = off_wiT + 1769472ULL;
  const size_t off_dirg = off_W0T + 32768ULL;
  const size_t off_wh8  = off_dirg + 16384ULL;            // 4 gates x 64 KB
  const size_t off_ext  = off_wh8 + 262144ULL;
  const size_t total    = off_ext + 131072ULL;            // 958,644,224
  if (ws_size < total) return;

  bf16* conv_out = (bf16*)(ws + off_conv);
  bf16* xg       = (bf16*)(ws + off_xg);
  bf16* wiT      = (bf16*)(ws + off_wiT);
  bf16* W0T      = (bf16*)(ws + off_W0T);
  float* dir_gate = (float*)(ws + off_dirg);
  unsigned char* wh8 = (unsigned char*)(ws + off_wh8);
  bf16* ext = (bf16*)(ws + off_ext);
  bf16* ys = (bf16*)(ws + 0);               // reuses conv_out region (dead after GEMM)

  float* out_cfin = (float*)d_out;
  float* out_hfin = out_cfin + 262144;
  float* out_logits = out_cfin + 524288;
  float* out_value = out_cfin + 524288 + 1835008;

  k_wiT<<<1024, 256, 0, stream>>>(wi, wiT);
  k_ext<<<256, 256, 0, stream>>>(context, ext);
  k_W0T<<<64, 256, 0, stream>>>(a0_k, cr0_k, W0T);
  k_dirgate<<<4, 256, 0, stream>>>(wi, emb_k, emb_b, b_lstm, dir_gate);
  k_wh8<<<256, 256, 0, stream>>>(wh, wh8);
  k_conv<<<MROWS / CONV_ROWS, 256, 0, stream>>>(image, conv_k, conv_b, conv_out);
  k_gemm_xg<<<16384, 256, 0, stream>>>(conv_out, ext, wiT, dir_gate, agent_dir, xg);
  k_lstm<<<64, 512, 0, stream>>>(xg, wh8, dones, c0, h0, ys, out_cfin, out_hfin);
  k_heads<<<2048, 256, 0, stream>>>(ys, W0T, a0_b, cr0_b, a1_k, a1_b, cr1_k, cr1_b,
                                    out_logits, out_value);
}

// Round 14
// 2429.124 us; speedup vs baseline: 8.1458x; 1.0531x over previous
//
#include <hip/hip_runtime.h>
#include <hip/hip_fp8.h>

typedef __bf16 bf16;
typedef __bf16 bf16x8 __attribute__((ext_vector_type(8)));
typedef __bf16 bf16x4 __attribute__((ext_vector_type(4)));
typedef float  f32x4  __attribute__((ext_vector_type(4)));

#define T_DIM 256
#define B_DIM 1024
#define HID   256
#define G4    1024
#define KIMG  784
#define KPAD  800
#define KEXT  864
#define CTXD  64
#define MROWS (T_DIM*B_DIM)
#define WPITCH 264

__device__ __forceinline__ void gll16(const void* g, void* l) {
  __builtin_amdgcn_global_load_lds((const __attribute__((address_space(1))) void*)g,
                                   (__attribute__((address_space(3))) void*)l, 16, 0, 0);
}
__device__ __forceinline__ float sigm(float x) { return 1.f / (1.f + __expf(-x)); }
__device__ __forceinline__ float tanh_(float x) {
  x = fminf(fmaxf(x, -15.f), 15.f);
  float e = __expf(2.f * x);
  return (e - 1.f) / (e + 1.f);
}
__device__ __forceinline__ void bar_lds() {
  asm volatile("s_waitcnt lgkmcnt(0)\n\ts_barrier" ::: "memory");
}
__device__ __forceinline__ unsigned char to_fp8(float f) {
  __hip_fp8_e4m3 v(f);
  return *reinterpret_cast<unsigned char*>(&v);
}

// ---------------- prep kernels ----------------
__global__ void k_wiT(const float* __restrict__ wi, bf16* __restrict__ wiT) {
  int n = blockIdx.x;
  for (int k = threadIdx.x; k < KEXT; k += 256) {
    float v = 0.f;
    if (k < KIMG) v = wi[(long)k * G4 + n];
    else if (k >= 800) v = wi[(long)(k - 11) * G4 + n];  // 789 + (k-800)
    wiT[(long)n * KEXT + k] = (bf16)v;
  }
}
__global__ void k_ext(const float* __restrict__ ctx, bf16* __restrict__ ext) {
  int idx = blockIdx.x * 256 + threadIdx.x;
  ext[idx] = (bf16)ctx[idx];
}
// fp8 e4m3 copies of ALL FOUR gate weight blocks, gate-major [g][n][k]
__global__ void k_wh8(const float* __restrict__ wh, unsigned char* __restrict__ wh8) {
  int n = blockIdx.x;
  int k = threadIdx.x;
#pragma unroll
  for (int g = 0; g < 4; ++g)
    wh8[g * 65536 + n * 256 + k] = to_fp8(wh[k * G4 + g * 256 + n]);
}
__global__ void k_W0T(const float* __restrict__ a0k, const float* __restrict__ cr0k,
                      bf16* __restrict__ w0t) {
  int n = blockIdx.x;
  int k = threadIdx.x;
  float v = (n < 32) ? a0k[k * 32 + n] : cr0k[k * 32 + (n - 32)];
  w0t[n * HID + k] = (bf16)v;
}
__global__ void k_dirgate(const float* __restrict__ wi, const float* __restrict__ emb_k,
                          const float* __restrict__ emb_b, const float* __restrict__ b_lstm,
                          float* __restrict__ dir_gate) {
  int d = blockIdx.x;
  for (int n = threadIdx.x; n < G4; n += 256) {
    float s = b_lstm[n];
#pragma unroll
    for (int j = 0; j < 5; ++j) s += (emb_k[d * 5 + j] + emb_b[j]) * wi[(KIMG + j) * G4 + n];
    dir_gate[d * G4 + n] = s;
  }
}

// ---------------- conv ----------------
#define CONV_ROWS 8
__global__ void k_conv(const float* __restrict__ img, const float* __restrict__ ck,
                       const float* __restrict__ cb, bf16* __restrict__ out) {
  __shared__ float s_img[CONV_ROWS * 243];
  __shared__ float s_k[432];
  __shared__ float s_b[16];
  long r0 = (long)blockIdx.x * CONV_ROWS;
  const float* src = img + r0 * 243;
  for (int i = threadIdx.x; i < CONV_ROWS * 243; i += 256) s_img[i] = src[i];
  for (int i = threadIdx.x; i < 432; i += 256) s_k[i] = ck[i];
  if (threadIdx.x < 16) s_b[threadIdx.x] = cb[threadIdx.x];
  __syncthreads();
  for (int idx = threadIdx.x; idx < CONV_ROWS * KPAD; idx += 256) {
    int r = idx / KPAD, c = idx % KPAD;
    float v = 0.f;
    if (c < KIMG) {
      int pix = c >> 4, ch = c & 15;
      int oy = pix / 7, ox = pix % 7;
      const float* ib = s_img + r * 243 + (oy * 9 + ox) * 3;
      v = s_b[ch];
#pragma unroll
      for (int ky = 0; ky < 3; ++ky)
#pragma unroll
        for (int kx = 0; kx < 3; ++kx)
#pragma unroll
          for (int cc = 0; cc < 3; ++cc)
            v += ib[(ky * 9 + kx) * 3 + cc] * s_k[((ky * 3 + kx) * 3 + cc) * 16 + ch];
      v = fmaxf(v, 0.f);
    }
    out[r0 * KPAD + idx] = (bf16)v;
  }
}

// ---------------- big GEMM: xg = [conv | ctx] @ wiT^T + dir_gate ----------
__global__ __launch_bounds__(256, 2)
void k_gemm_xg(const bf16* __restrict__ A, const bf16* __restrict__ ext,
               const bf16* __restrict__ Bt, const float* __restrict__ dir_gate,
               const int* __restrict__ agent_dir, bf16* __restrict__ xg) {
  __shared__ __align__(16) bf16 As[128 * 32];
  __shared__ __align__(16) bf16 Bs[128 * 32];
  const int bid = blockIdx.x;
  const int xcd = bid & 7, local = bid >> 3;
  const long m0 = (long)(xcd * 256 + (local >> 3)) * 128;
  const int n0 = (local & 7) * 128;
  const int tid = threadIdx.x, wave = tid >> 6, lane = tid & 63;
  const int row16 = lane & 15, k8 = (lane >> 4) * 8, rowg = (lane >> 4) * 4;
  const int wr = (wave >> 1) * 64, wc = (wave & 1) * 64;

  const bf16* a_src0 = A + (m0 + tid / 4) * KPAD + (tid % 4) * 8;
  const bf16* a_src1 = A + (m0 + 64 + tid / 4) * KPAD + (tid % 4) * 8;
  const bf16* e_src0 = ext + (long)(((m0) & 1023) + tid / 4) * CTXD + (tid % 4) * 8;
  const bf16* e_src1 = ext + (long)(((m0 + 64) & 1023) + tid / 4) * CTXD + (tid % 4) * 8;
  const bf16* b_src0 = Bt + (long)(n0 + tid / 4) * KEXT + (tid % 4) * 8;
  const bf16* b_src1 = Bt + (long)(n0 + 64 + tid / 4) * KEXT + (tid % 4) * 8;
  bf16* asd0 = As + wave * 512;
  bf16* asd1 = As + 2048 + wave * 512;
  bf16* bsd0 = Bs + wave * 512;
  bf16* bsd1 = Bs + 2048 + wave * 512;

  f32x4 acc[4][4];
  const f32x4 zero = {0.f, 0.f, 0.f, 0.f};
#pragma unroll
  for (int i = 0; i < 4; ++i)
#pragma unroll
    for (int j = 0; j < 4; ++j) acc[i][j] = zero;

  for (int ks = 0; ks < 27; ++ks) {
    if (ks < 25) {
      const int ko = ks * 32;
      gll16(a_src0 + ko, asd0);
      gll16(a_src1 + ko, asd1);
    } else {
      const int ko = (ks - 25) * 32;
      gll16(e_src0 + ko, asd0);
      gll16(e_src1 + ko, asd1);
    }
    const int kb = ks * 32;
    gll16(b_src0 + kb, bsd0);
    gll16(b_src1 + kb, bsd1);
    __syncthreads();
    bf16x8 af[4], bfr[4];
#pragma unroll
    for (int i = 0; i < 4; ++i)
      af[i] = *(const bf16x8*)(As + (wr + 16 * i + row16) * 32 + k8);
#pragma unroll
    for (int j = 0; j < 4; ++j)
      bfr[j] = *(const bf16x8*)(Bs + (wc + 16 * j + row16) * 32 + k8);
#pragma unroll
    for (int i = 0; i < 4; ++i)
#pragma unroll
      for (int j = 0; j < 4; ++j)
        acc[i][j] = __builtin_amdgcn_mfma_f32_16x16x32_bf16(af[i], bfr[j], acc[i][j], 0, 0, 0);
    __syncthreads();
  }
#pragma unroll
  for (int i = 0; i < 4; ++i)
#pragma unroll
    for (int j = 0; j < 4; ++j)
#pragma unroll
      for (int r = 0; r < 4; ++r) {
        long row = m0 + wr + 16 * i + rowg + r;
        int colj = n0 + wc + 16 * j + row16;
        int dv = agent_dir[row];
        float base = dir_gate[dv * G4 + colj];
        int u = colj & 255, g = colj >> 8;
        xg[row * G4 + u * 4 + g] = (bf16)(acc[i][j][r] + base);
      }
}

// ---------------- LSTM scan: all-fp8, 16 waves (4/SIMD) ----------------
// 64 blocks x 1024 threads. Wave w owns units [16w, 16w+16) — q eliminated,
// per-wave VGPR demand ~75 (fits 4 waves/SIMD at the 128 cap; R7's failure
// was the 64-cap at 115 demand). Gates i,g fp8 LDS-resident; f,o fp8
// streamed (wrap-around dist-1); h fp8 in LDS. Raw lgkm-only barriers.
__global__ __launch_bounds__(1024)
void k_lstm(const bf16* __restrict__ xg, const unsigned char* __restrict__ wh8,
            const int* __restrict__ dones,
            const float* __restrict__ c0, const float* __restrict__ h0,
            bf16* __restrict__ ys, float* __restrict__ cfin, float* __restrict__ hfin) {
  __shared__ __align__(16) unsigned char wi8_lds[256 * WPITCH];  // gate i
  __shared__ __align__(16) unsigned char wg8_lds[256 * WPITCH];  // gate g
  __shared__ __align__(16) unsigned char h8_lds[16 * WPITCH];
  const int tid = threadIdx.x;
  const int w = tid >> 6, lane = tid & 63;
  const int col = lane & 15;
  const int kq = lane >> 4;
  const int k8 = kq * 8;
  const int rowg = kq * 4;
  const int b0 = blockIdx.x * 16;
  const int ju = 16 * w + col;      // this thread's unit

  // resident fp8 weight fills (gates i and g)
  for (int i = tid; i < 256 * 32; i += 1024) {
    int row = i >> 5, c = i & 31;
    *(long long*)(wi8_lds + row * WPITCH + c * 8) =
        *(const long long*)(wh8 + row * 256 + c * 8);
    *(long long*)(wg8_lds + row * WPITCH + c * 8) =
        *(const long long*)(wh8 + 2 * 65536 + row * 256 + c * 8);
  }
  for (int i = tid; i < 16 * HID; i += 1024) {
    int m = i >> 8, j = i & 255;
    h8_lds[m * WPITCH + j] = to_fp8(h0[(b0 + m) * HID + j]);
  }

  float creg[4], c0reg[4];
  unsigned char h0b8[4];
#pragma unroll
  for (int r = 0; r < 4; ++r) {
    float v = c0[(b0 + rowg + r) * HID + ju];
    creg[r] = v; c0reg[r] = v;
    h0b8[r] = to_fp8(h0[(b0 + rowg + r) * HID + ju]);
  }
  // stream bases: f (gate 1), o (gate 3)
  const unsigned char* wfp = wh8 + 1 * 65536 + ju * 256 + k8;
  const unsigned char* wop = wh8 + 3 * 65536 + ju * 256 + k8;

  int4 dnA = *(const int4*)(dones + b0 + rowg);
  bf16x4 xc[4];
  {
    const bf16* xb = xg + (long)(b0 + rowg) * G4 + ju * 4;
#pragma unroll
    for (int r = 0; r < 4; ++r)
      xc[r] = *(const bf16x4*)(xb + (long)r * G4);
  }
  long long bf_cur, bf_nxt, bo_cur, bo_nxt;
  bf_cur = *(const long long*)(wfp);
  bo_cur = *(const long long*)(wop);
  __syncthreads();

#pragma unroll 1
  for (int t = 0; t < T_DIM; ++t) {
    const int tn = (t + 1 < T_DIM) ? t + 1 : (T_DIM - 1);
    f32x4 acc[4];
    const f32x4 zero = {0.f, 0.f, 0.f, 0.f};
#pragma unroll
    for (int g = 0; g < 4; ++g) acc[g] = zero;

    int4 dnB;
#pragma unroll
    for (int ks = 0; ks < 8; ++ks) {
      // wrap-around distance-1 prefetch for streamed f,o
      {
        const int kn = (ks + 1) & 7;
        bf_nxt = *(const long long*)(wfp + kn * 32);
        bo_nxt = *(const long long*)(wop + kn * 32);
      }
      long long a8 = *(const long long*)(h8_lds + col * WPITCH + ks * 32 + k8);
      long long bi8 = *(const long long*)(wi8_lds + ju * WPITCH + ks * 32 + k8);
      long long bg8 = *(const long long*)(wg8_lds + ju * WPITCH + ks * 32 + k8);
      acc[0] = __builtin_amdgcn_mfma_f32_16x16x32_fp8_fp8(a8, bi8, acc[0], 0, 0, 0);
      acc[1] = __builtin_amdgcn_mfma_f32_16x16x32_fp8_fp8(a8, bf_cur, acc[1], 0, 0, 0);
      acc[2] = __builtin_amdgcn_mfma_f32_16x16x32_fp8_fp8(a8, bg8, acc[2], 0, 0, 0);
      acc[3] = __builtin_amdgcn_mfma_f32_16x16x32_fp8_fp8(a8, bo_cur, acc[3], 0, 0, 0);
      bf_cur = bf_nxt; bo_cur = bo_nxt;
      if (ks == 2)
        dnB = *(const int4*)(dones + (long)tn * B_DIM + b0 + rowg);
    }
    bar_lds();   // h8_lds reads complete; global loads stay in flight

    int dc[4] = {dnA.x, dnA.y, dnA.z, dnA.w};
    int dx[4] = {dnB.x, dnB.y, dnB.z, dnB.w};
#pragma unroll
    for (int r = 0; r < 4; ++r) {
      float c_old = dc[r] ? c0reg[r] : creg[r];
      float gi = acc[0][r] + (float)xc[r][0];
      float gf = acc[1][r] + (float)xc[r][1];
      float gg = acc[2][r] + (float)xc[r][2];
      float go = acc[3][r] + (float)xc[r][3];
      float cn = sigm(gf) * c_old + sigm(gi) * tanh_(gg);
      float hn = sigm(go) * tanh_(cn);
      creg[r] = cn;
      int m = rowg + r;
      ys[((long)t * B_DIM + b0 + m) * HID + ju] = (bf16)hn;
      h8_lds[m * WPITCH + ju] = dx[r] ? h0b8[r] : to_fp8(hn);
      if (t == T_DIM - 1) {
        cfin[(b0 + m) * HID + ju] = cn;
        hfin[(b0 + m) * HID + ju] = hn;
      }
    }
    // prefetch next step's xg (consumed next epilogue)
    {
      const bf16* xb = xg + (long)(tn * B_DIM + b0 + rowg) * G4 + ju * 4;
#pragma unroll
      for (int r = 0; r < 4; ++r)
        xc[r] = *(const bf16x4*)(xb + (long)r * G4);
    }
    dnA = dnB;
    bar_lds();   // h8 writes visible for next step's GEMM
  }
}

// ---------------- fused heads ----------------
#define H1PITCH 66
__global__ __launch_bounds__(256, 2)
void k_heads(const bf16* __restrict__ ys, const bf16* __restrict__ w0t,
             const float* __restrict__ a0b, const float* __restrict__ cr0b,
             const float* __restrict__ a1k, const float* __restrict__ a1b,
             const float* __restrict__ cr1k, const float* __restrict__ cr1b,
             float* __restrict__ logits, float* __restrict__ value) {
  __shared__ __align__(16) bf16 As[128 * 32];
  __shared__ __align__(16) bf16 Ws[64 * 264];
  __shared__ bf16 h1_lds[128 * H1PITCH];
  __shared__ float w2[32 * 8];
  const int tid = threadIdx.x, wave = tid >> 6, lane = tid & 63;
  const int row16 = lane & 15, k8 = (lane >> 4) * 8, rowg = (lane >> 4) * 4;
  const long m0 = (long)blockIdx.x * 128;
  for (int i = tid; i < 64 * 256; i += 256) {
    int n = i >> 8, k = i & 255;
    Ws[n * 264 + k] = w0t[i];
  }
  if (tid < 224) { int k = tid / 7, c = tid % 7; w2[k * 8 + c] = a1k[tid]; }
  else if (tid < 256) { int k = tid - 224; w2[k * 8 + 7] = cr1k[k]; }
  const bf16* a_src0 = ys + (m0 + tid / 4) * HID + (tid % 4) * 8;
  const bf16* a_src1 = ys + (m0 + 64 + tid / 4) * HID + (tid % 4) * 8;
  bf16* asd0 = As + wave * 512;
  bf16* asd1 = As + 2048 + wave * 512;
  f32x4 acc[2][4];
  const f32x4 zero = {0.f, 0.f, 0.f, 0.f};
#pragma unroll
  for (int i = 0; i < 2; ++i)
#pragma unroll
    for (int j = 0; j < 4; ++j) acc[i][j] = zero;
  for (int ks = 0; ks < 8; ++ks) {
    gll16(a_src0 + ks * 32, asd0);
    gll16(a_src1 + ks * 32, asd1);
    __syncthreads();
    bf16x8 bw[4];
#pragma unroll
    for (int j = 0; j < 4; ++j)
      bw[j] = *(const bf16x8*)(Ws + (16 * j + row16) * 264 + ks * 32 + k8);
#pragma unroll
    for (int i = 0; i < 2; ++i) {
      bf16x8 a = *(const bf16x8*)(As + (32 * wave + 16 * i + row16) * 32 + k8);
#pragma unroll
      for (int j = 0; j < 4; ++j)
        acc[i][j] = __builtin_amdgcn_mfma_f32_16x16x32_bf16(a, bw[j], acc[i][j], 0, 0, 0);
    }
    __syncthreads();
  }
#pragma unroll
  for (int i = 0; i < 2; ++i)
#pragma unroll
    for (int j = 0; j < 4; ++j)
#pragma unroll
      for (int r = 0; r < 4; ++r) {
        int rl = 32 * wave + 16 * i + rowg + r;
        int n = 16 * j + row16;
        float bias = (n < 32) ? a0b[n] : cr0b[n - 32];
        h1_lds[rl * H1PITCH + n] = (bf16)fmaxf(acc[i][j][r] + bias, 0.f);
      }
  __syncthreads();
  if (tid < 128) {
    const bf16* hp = h1_lds + tid * H1PITCH;
    float acc7[7];
#pragma unroll
    for (int c = 0; c < 7; ++c) acc7[c] = a1b[c];
    float accv = cr1b[0];
#pragma unroll 4
    for (int k = 0; k < 32; ++k) {
      float av = (float)hp[k];
      float cv = (float)hp[32 + k];
#pragma unroll
      for (int c = 0; c < 7; ++c) acc7[c] += av * w2[k * 8 + c];
      accv += cv * w2[k * 8 + 7];
    }
    long row = m0 + tid;
#pragma unroll
    for (int c = 0; c < 7; ++c) logits[row * 7 + c] = acc7[c];
    value[row] = accv;
  }
}

// ---------------- launch ----------------
extern "C" void kernel_launch(void* const* d_in, const int* in_sizes, int n_in,
                              void* d_out, int out_size, void* d_ws, size_t ws_size,
                              hipStream_t stream) {
  const float* image = (const float*)d_in[0];
  const int* agent_dir = (const int*)d_in[1];
  const int* dones = (const int*)d_in[2];
  const float* context = (const float*)d_in[3];
  const float* c0 = (const float*)d_in[4];
  const float* h0 = (const float*)d_in[5];
  const float* conv_k = (const float*)d_in[6];
  const float* conv_b = (const float*)d_in[7];
  const float* emb_k = (const float*)d_in[8];
  const float* emb_b = (const float*)d_in[9];
  const float* wi = (const float*)d_in[10];
  const float* wh = (const float*)d_in[11];
  const float* b_lstm = (const float*)d_in[12];
  const float* a0_k = (const float*)d_in[13];
  const float* a0_b = (const float*)d_in[14];
  const float* a1_k = (const float*)d_in[15];
  const float* a1_b = (const float*)d_in[16];
  const float* cr0_k = (const float*)d_in[17];
  const float* cr0_b = (const float*)d_in[18];
  const float* cr1_k = (const float*)d_in[19];
  const float* cr1_b = (const float*)d_in[20];

  char* ws = (char*)d_ws;
  const size_t off_conv = 0;                              // 419,430,400 (ys reuse)
  const size_t off_xg   = 419430400ULL;                   // 512 MB
  const size_t off_wiT  = off_xg  + 536870912ULL;         // 1024*864*2
  const size_t off_W0T  = off_wiT + 1769472ULL;
  const size_t off_dirg = off_W0T + 32768ULL;
  const size_t off_wh8  = off_dirg + 16384ULL;            // 4 gates x 64 KB
  const size_t off_ext  = off_wh8 + 262144ULL;
  const size_t total    = off_ext + 131072ULL;            // 958,644,224
  if (ws_size < total) return;

  bf16* conv_out = (bf16*)(ws + off_conv);
  bf16* xg       = (bf16*)(ws + off_xg);
  bf16* wiT      = (bf16*)(ws + off_wiT);
  bf16* W0T      = (bf16*)(ws + off_W0T);
  float* dir_gate = (float*)(ws + off_dirg);
  unsigned char* wh8 = (unsigned char*)(ws + off_wh8);
  bf16* ext = (bf16*)(ws + off_ext);
  bf16* ys = (bf16*)(ws + 0);               // reuses conv_out region (dead after GEMM)

  float* out_cfin = (float*)d_out;
  float* out_hfin = out_cfin + 262144;
  float* out_logits = out_cfin + 524288;
  float* out_value = out_cfin + 524288 + 1835008;

  k_wiT<<<1024, 256, 0, stream>>>(wi, wiT);
  k_ext<<<256, 256, 0, stream>>>(context, ext);
  k_W0T<<<64, 256, 0, stream>>>(a0_k, cr0_k, W0T);
  k_dirgate<<<4, 256, 0, stream>>>(wi, emb_k, emb_b, b_lstm, dir_gate);
  k_wh8<<<256, 256, 0, stream>>>(wh, wh8);
  k_conv<<<MROWS / CONV_ROWS, 256, 0, stream>>>(image, conv_k, conv_b, conv_out);
  k_gemm_xg<<<16384, 256, 0, stream>>>(conv_out, ext, wiT, dir_gate, agent_dir, xg);
  k_lstm<<<64, 1024, 0, stream>>>(xg, wh8, dones, c0, h0, ys, out_cfin, out_hfin);
  k_heads<<<2048, 256, 0, stream>>>(ys, W0T, a0_b, cr0_b, a1_k, a1_b, cr1_k, cr1_b,
                                    out_logits, out_value);
}